// Round 6
// baseline (147.828 us; speedup 1.0000x reference)
//
#include <hip/hip_runtime.h>

// LocalAttention, MFMA bf16, round 6: software-pipelined persistent sweep.
// B=4, L=2048, H=16, E=D=64, window=64. fp32 in/out; bf16 MFMA; fp32 accumulate.
//
// Round-6 change vs round 5: each block sweeps NTILES=4 consecutive 64-query
// tiles (grid 512 = 2 blocks/CU). Tile i+1's global loads are issued right
// after the pack-barrier of tile i and consumed at the NEXT pack -> load
// latency is hidden under tile i's compute. __syncthreads() would drain
// vmcnt(0) and defeat the prefetch, so barriers are inline-asm
// "s_waitcnt lgkmcnt(0); s_barrier" (LDS visibility only; global loads to
// VGPRs ride through). 2 barriers/iter keep wave skew < 1 iter -> single
// LDS buffer is safe.
//
// LDS = Ks 128x72 + Vt 64x152 + P 4x16x104 (bf16) = 50 KB.

#define B_ 4
#define L_ 2048
#define H_ 16
#define E_ 64
#define D_ 64
#define KS_STRIDE 72
#define VT_STRIDE 152
#define P_STRIDE 104
#define NTILES 4

typedef __attribute__((ext_vector_type(8))) short short8;
typedef __attribute__((ext_vector_type(4))) float f32x4;

__device__ __forceinline__ unsigned int f2bf(float x) {
  unsigned int b = __float_as_uint(x);
  b += 0x7fffu + ((b >> 16) & 1u);   // RNE to bf16
  return b >> 16;
}
__device__ __forceinline__ unsigned int pack2(float a, float b) {
  return f2bf(a) | (f2bf(b) << 16);
}
__device__ __forceinline__ short8 pack8(const float4& a, const float4& b) {
  union { short8 s; uint4 u; } r;
  r.u = make_uint4(pack2(a.x, a.y), pack2(a.z, a.w), pack2(b.x, b.y), pack2(b.z, b.w));
  return r.s;
}
// Barrier with LDS-visibility only: waits lgkmcnt(0), NOT vmcnt -> in-flight
// global prefetch loads survive the rendezvous.
__device__ __forceinline__ void barrier_lgkm() {
  asm volatile("s_waitcnt lgkmcnt(0)\n\ts_barrier" ::: "memory");
}

__global__ __launch_bounds__(256, 2)
void local_attn_mfma(const float* __restrict__ qg,
                     const float* __restrict__ kg,
                     const float* __restrict__ vg,
                     float* __restrict__ og) {
  __shared__ __align__(16) unsigned short Ks[128 * KS_STRIDE];   // [key_rel][dim]
  __shared__ __align__(16) unsigned short Vt[64 * VT_STRIDE];    // [dim][key_rel]
  __shared__ __align__(16) unsigned short Pl[4 * 16 * P_STRIDE]; // per-wave P tile

  const int t = threadIdx.x;
  const int qbase = blockIdx.x * (NTILES * 64);
  const int h = blockIdx.y;
  const int b = blockIdx.z;
  const int wave = t >> 6;
  const int lane = t & 63;
  const int col16 = lane & 15;
  const int quad = lane >> 4;
  const int kp = t >> 2;               // V staging: key pair id
  const int dq = t & 3;                // V staging: dim quarter
  const float4 fzero = make_float4(0.f, 0.f, 0.f, 0.f);

  float4 kf[8], va[4], vc[4], qf[4];

  auto load_tile = [&](int q0) {
    const int ks0 = q0 - 32;
    // K: coalesced — 16 consecutive lanes sweep one 64-float row.
    #pragma unroll
    for (int itr = 0; itr < 8; ++itr) {
      int cid = t + itr * 256;
      int row = cid >> 4, ch = cid & 15;
      int key = ks0 + row;
      kf[itr] = (key >= 0 && key < L_)
        ? *(const float4*)(kg + ((size_t)(b * L_ + key) * H_ + h) * E_ + ch * 4)
        : fzero;
    }
    // V: 4 lanes cover one key row (2 keys/thread x 16-dim quarters).
    int k0 = ks0 + 2 * kp, k1 = k0 + 1;
    #pragma unroll
    for (int i = 0; i < 4; ++i) { va[i] = fzero; vc[i] = fzero; }
    if (k0 >= 0 && k0 < L_) {
      const float* p = vg + ((size_t)(b * L_ + k0) * H_ + h) * D_ + dq * 16;
      #pragma unroll
      for (int i = 0; i < 4; ++i) va[i] = *(const float4*)(p + i * 4);
    }
    if (k1 >= 0 && k1 < L_) {
      const float* p = vg + ((size_t)(b * L_ + k1) * H_ + h) * D_ + dq * 16;
      #pragma unroll
      for (int i = 0; i < 4; ++i) vc[i] = *(const float4*)(p + i * 4);
    }
    // Q A-frag source: one row-read per lane (each Q row read exactly once).
    const float* p = qg + ((size_t)(b * L_ + q0 + wave * 16 + col16) * H_ + h) * E_ + quad * 8;
    qf[0] = *(const float4*)p;
    qf[1] = *(const float4*)(p + 4);
    qf[2] = *(const float4*)(p + 32);
    qf[3] = *(const float4*)(p + 36);
  };

  load_tile(qbase);   // prologue: tile 0 loads (only these are latency-exposed)

  #pragma unroll
  for (int it = 0; it < NTILES; ++it) {
    const int q0 = qbase + it * 64;
    const int kstart = q0 - 32;

    // ---- Pack tile-it regs -> LDS (vmcnt waits happen here, one tile late) ----
    #pragma unroll
    for (int itr = 0; itr < 8; ++itr) {
      int cid = t + itr * 256;
      int row = cid >> 4, ch = cid & 15;
      float4 f = kf[itr];
      *(uint2*)&Ks[row * KS_STRIDE + ch * 4] = make_uint2(pack2(f.x, f.y), pack2(f.z, f.w));
    }
    #pragma unroll
    for (int i = 0; i < 4; ++i) {
      float av[4] = {va[i].x, va[i].y, va[i].z, va[i].w};
      float cv[4] = {vc[i].x, vc[i].y, vc[i].z, vc[i].w};
      #pragma unroll
      for (int j = 0; j < 4; ++j) {
        int d = dq * 16 + i * 4 + j;
        *(unsigned int*)&Vt[d * VT_STRIDE + 2 * kp] = pack2(av[j], cv[j]);
      }
    }
    // zero pad Vt key cols 128..143 (PV K-overhang; P there is 0)
    *(uint2*)&Vt[(t >> 2) * VT_STRIDE + 128 + (t & 3) * 4] = make_uint2(0u, 0u);

    const short8 qa0 = pack8(qf[0], qf[1]);   // consume qf before prefetch clobbers
    const short8 qa1 = pack8(qf[2], qf[3]);

    barrier_lgkm();   // LDS tile visible to all waves; no vmcnt drain

    // ---- Prefetch tile it+1 (in flight across all of tile-it's compute) ----
    if (it + 1 < NTILES) load_tile(qbase + (it + 1) * 64);

    // ---- QK: 5 key-tiles; B-frags from Ks ----
    f32x4 acc[5];
    #pragma unroll
    for (int tt = 0; tt < 5; ++tt) {
      int krow = wave * 16 + tt * 16 + col16;
      short8 b0 = *(const short8*)&Ks[krow * KS_STRIDE + quad * 8];
      short8 b1 = *(const short8*)&Ks[krow * KS_STRIDE + quad * 8 + 32];
      f32x4 c = {0.f, 0.f, 0.f, 0.f};
      c = __builtin_amdgcn_mfma_f32_16x16x32_bf16(qa0, b0, c, 0, 0, 0);
      c = __builtin_amdgcn_mfma_f32_16x16x32_bf16(qa1, b1, c, 0, 0, 0);
      acc[tt] = c;
    }

    // ---- Mask + softmax in registers. C layout: row=quad*4+r, col=col16 ----
    #pragma unroll
    for (int r = 0; r < 4; ++r) {
      const int row_loc = quad * 4 + r;
      float x[5];
      #pragma unroll
      for (int tt = 0; tt < 5; ++tt) {
        int c_loc = tt * 16 + col16;
        int gkey = kstart + wave * 16 + c_loc;
        bool ok = (c_loc >= row_loc) && (c_loc < row_loc + 64) && (gkey >= 0) && (gkey < L_);
        x[tt] = ok ? acc[tt][r] * 0.125f : -1e30f;   // scale = 1/sqrt(64)
      }
      float m = fmaxf(fmaxf(fmaxf(x[0], x[1]), fmaxf(x[2], x[3])), x[4]);
      m = fmaxf(m, __shfl_xor(m, 1));
      m = fmaxf(m, __shfl_xor(m, 2));
      m = fmaxf(m, __shfl_xor(m, 4));
      m = fmaxf(m, __shfl_xor(m, 8));
      float s = 0.f;
      #pragma unroll
      for (int tt = 0; tt < 5; ++tt) { x[tt] = __expf(x[tt] - m); s += x[tt]; }
      s += __shfl_xor(s, 1);
      s += __shfl_xor(s, 2);
      s += __shfl_xor(s, 4);
      s += __shfl_xor(s, 8);
      float inv = 1.0f / s;
      #pragma unroll
      for (int tt = 0; tt < 5; ++tt) acc[tt][r] = x[tt] * inv;
    }

    // ---- P -> LDS (own-wave region; within-wave lgkm ordering suffices) ----
    unsigned short* Pw = &Pl[wave * 16 * P_STRIDE];
    *(uint2*)&Pw[col16 * P_STRIDE + 80 + quad * 4] = make_uint2(0u, 0u);
    #pragma unroll
    for (int tt = 0; tt < 5; ++tt)
      #pragma unroll
      for (int r = 0; r < 4; ++r)
        Pw[(quad * 4 + r) * P_STRIDE + tt * 16 + col16] = (unsigned short)f2bf(acc[tt][r]);

    // ---- PV: A=P[16 x 96], B=Vt keys [wave*16, wave*16+96) x 64 dims ----
    f32x4 oacc[4];
    #pragma unroll
    for (int nt = 0; nt < 4; ++nt) oacc[nt] = (f32x4){0.f, 0.f, 0.f, 0.f};
    #pragma unroll
    for (int ks = 0; ks < 3; ++ks) {
      short8 pa = *(const short8*)&Pw[col16 * P_STRIDE + ks * 32 + quad * 8];
      #pragma unroll
      for (int nt = 0; nt < 4; ++nt) {
        short8 vb = *(const short8*)&Vt[(nt * 16 + col16) * VT_STRIDE + wave * 16 + ks * 32 + quad * 8];
        oacc[nt] = __builtin_amdgcn_mfma_f32_16x16x32_bf16(pa, vb, oacc[nt], 0, 0, 0);
      }
    }

    // ---- Store O (fp32). C layout: row=quad*4+r (query), col=col16 ----
    #pragma unroll
    for (int r = 0; r < 4; ++r) {
      int q = q0 + wave * 16 + quad * 4 + r;
      float* orow = og + ((size_t)(b * L_ + q) * H_ + h) * D_;
      #pragma unroll
      for (int nt = 0; nt < 4; ++nt)
        orow[nt * 16 + col16] = oacc[nt][r];
    }

    barrier_lgkm();   // all waves' Ks/Vt reads retired before next pack
  }
}

extern "C" void kernel_launch(void* const* d_in, const int* in_sizes, int n_in,
                              void* d_out, int out_size, void* d_ws, size_t ws_size,
                              hipStream_t stream) {
  const float* q = (const float*)d_in[0];
  const float* k = (const float*)d_in[1];
  const float* v = (const float*)d_in[2];
  float* o = (float*)d_out;
  dim3 grid(L_ / (NTILES * 64), H_, B_);   // 8 x 16 x 4 = 512 blocks
  local_attn_mfma<<<grid, dim3(256), 0, stream>>>(q, k, v, o);
}

// Round 7
// 140.445 us; speedup vs baseline: 1.0526x; 1.0526x over previous
//
#include <hip/hip_runtime.h>

// LocalAttention, MFMA bf16, round 7 = round 5 + forced load batching.
// B=4, L=2048, H=16, E=D=64, window=64. fp32 in/out; bf16 MFMA; fp32 accumulate.
//
// Round-5 plateau diagnosis: VGPR_Count=68 proves the compiler serialized the
// 28 staging loads into load->wait->pack chunks (~4-8 KB in flight per wave),
// starving the per-CU HBM share (measured 2.7 of ~6.3 TB/s). Fix: a
// sched_barrier(0) fence after load issuance pins ALL loads before ANY pack,
// raising in-flight bytes to ~28 KB/wave. launch_bounds(256,3) permits ~170
// VGPRs so the ~112 live load regs fit without spill.
//
// Structure otherwise identical to round 5:
//   - K staged coalesced -> LDS natural layout [key][dim].
//   - V staged (2 keys x 16-dim quarters per lane) -> LDS transposed [dim][key].
//   - Q A-frags direct from global (each Q row read once).
//   - One __syncthreads; per-wave P -> LDS; 5 QK + 12 PV MFMAs per wave.
// LDS = Ks 128x72 + Vt 64x152 + P 4x16x104 (bf16) = 50 KB -> 3 blocks/CU.

#define B_ 4
#define L_ 2048
#define H_ 16
#define E_ 64
#define D_ 64
#define KS_STRIDE 72
#define VT_STRIDE 152
#define P_STRIDE 104

typedef __attribute__((ext_vector_type(8))) short short8;
typedef __attribute__((ext_vector_type(4))) float f32x4;

__device__ __forceinline__ unsigned int f2bf(float x) {
  unsigned int b = __float_as_uint(x);
  b += 0x7fffu + ((b >> 16) & 1u);   // RNE to bf16
  return b >> 16;
}
__device__ __forceinline__ unsigned int pack2(float a, float b) {
  return f2bf(a) | (f2bf(b) << 16);
}
__device__ __forceinline__ short8 pack8(const float4& a, const float4& b) {
  union { short8 s; uint4 u; } r;
  r.u = make_uint4(pack2(a.x, a.y), pack2(a.z, a.w), pack2(b.x, b.y), pack2(b.z, b.w));
  return r.s;
}

__global__ __launch_bounds__(256, 3)
void local_attn_mfma(const float* __restrict__ qg,
                     const float* __restrict__ kg,
                     const float* __restrict__ vg,
                     float* __restrict__ og) {
  __shared__ __align__(16) unsigned short Ks[128 * KS_STRIDE];   // [key_rel][dim]
  __shared__ __align__(16) unsigned short Vt[64 * VT_STRIDE];    // [dim][key_rel]
  __shared__ __align__(16) unsigned short Pl[4 * 16 * P_STRIDE]; // per-wave P tile

  const int t = threadIdx.x;
  const int q0 = blockIdx.x * 64;
  const int h = blockIdx.y;
  const int b = blockIdx.z;
  const int kstart = q0 - 32;
  const int wave = t >> 6;
  const int lane = t & 63;
  const int col16 = lane & 15;
  const int quad = lane >> 4;

  const float4 fzero = make_float4(0.f, 0.f, 0.f, 0.f);

  // ---- Issue ALL global loads (coalesced K, transposing V, direct Q) ----
  float4 kf[8];
  #pragma unroll
  for (int it = 0; it < 8; ++it) {
    int cid = t + it * 256;            // 128 rows x 16 float4-chunks
    int row = cid >> 4, ch = cid & 15;
    int key = kstart + row;
    kf[it] = (key >= 0 && key < L_)
      ? *(const float4*)(kg + ((size_t)(b * L_ + key) * H_ + h) * E_ + ch * 4)
      : fzero;
  }
  const int kp = t >> 2;               // key pair -> keys kstart+2kp, +2kp+1
  const int dq = t & 3;                // dim quarter: dims dq*16 .. +15
  float4 va[4], vc[4];
  {
    int k0 = kstart + 2 * kp, k1 = k0 + 1;
    #pragma unroll
    for (int i = 0; i < 4; ++i) { va[i] = fzero; vc[i] = fzero; }
    if (k0 >= 0 && k0 < L_) {
      const float* p = vg + ((size_t)(b * L_ + k0) * H_ + h) * D_ + dq * 16;
      #pragma unroll
      for (int i = 0; i < 4; ++i) va[i] = *(const float4*)(p + i * 4);
    }
    if (k1 >= 0 && k1 < L_) {
      const float* p = vg + ((size_t)(b * L_ + k1) * H_ + h) * D_ + dq * 16;
      #pragma unroll
      for (int i = 0; i < 4; ++i) vc[i] = *(const float4*)(p + i * 4);
    }
  }
  float4 qf0, qf1, qf2, qf3;
  {
    const float* p = qg + ((size_t)(b * L_ + q0 + wave * 16 + col16) * H_ + h) * E_ + quad * 8;
    qf0 = *(const float4*)p;
    qf1 = *(const float4*)(p + 4);
    qf2 = *(const float4*)(p + 32);
    qf3 = *(const float4*)(p + 36);
  }

  // ---- FENCE: nothing (packs/LDS writes) may be hoisted above; all 28 loads
  //      are issued and in flight before the first vmcnt wait. ----
  __builtin_amdgcn_sched_barrier(0);

  // ---- Pack + LDS writes ----
  #pragma unroll
  for (int it = 0; it < 8; ++it) {
    int cid = t + it * 256;
    int row = cid >> 4, ch = cid & 15;
    float4 f = kf[it];
    *(uint2*)&Ks[row * KS_STRIDE + ch * 4] = make_uint2(pack2(f.x, f.y), pack2(f.z, f.w));
  }
  #pragma unroll
  for (int i = 0; i < 4; ++i) {
    float av[4] = {va[i].x, va[i].y, va[i].z, va[i].w};
    float cv[4] = {vc[i].x, vc[i].y, vc[i].z, vc[i].w};
    #pragma unroll
    for (int j = 0; j < 4; ++j) {
      int d = dq * 16 + i * 4 + j;
      *(unsigned int*)&Vt[d * VT_STRIDE + 2 * kp] = pack2(av[j], cv[j]);
    }
  }
  // zero pad Vt key cols 128..143 (PV K-overhang reads them; P there is 0)
  *(uint2*)&Vt[(t >> 2) * VT_STRIDE + 128 + (t & 3) * 4] = make_uint2(0u, 0u);

  const short8 qa0 = pack8(qf0, qf1);
  const short8 qa1 = pack8(qf2, qf3);
  __syncthreads();

  // ---- QK: 5 key-tiles; B-frags from Ks (ds_read_b128) ----
  f32x4 acc[5];
  #pragma unroll
  for (int tt = 0; tt < 5; ++tt) {
    int krow = wave * 16 + tt * 16 + col16;     // B: n=key, k=quad*8+j (E-dim)
    short8 b0 = *(const short8*)&Ks[krow * KS_STRIDE + quad * 8];
    short8 b1 = *(const short8*)&Ks[krow * KS_STRIDE + quad * 8 + 32];
    f32x4 c = {0.f, 0.f, 0.f, 0.f};
    c = __builtin_amdgcn_mfma_f32_16x16x32_bf16(qa0, b0, c, 0, 0, 0);
    c = __builtin_amdgcn_mfma_f32_16x16x32_bf16(qa1, b1, c, 0, 0, 0);
    acc[tt] = c;
  }

  // ---- Mask + softmax in registers. C layout: row=quad*4+r, col=col16 ----
  #pragma unroll
  for (int r = 0; r < 4; ++r) {
    const int row_loc = quad * 4 + r;
    float x[5];
    #pragma unroll
    for (int tt = 0; tt < 5; ++tt) {
      int c_loc = tt * 16 + col16;                    // key rel to M-tile start
      int gkey = kstart + wave * 16 + c_loc;          // global key
      bool ok = (c_loc >= row_loc) && (c_loc < row_loc + 64) && (gkey >= 0) && (gkey < L_);
      x[tt] = ok ? acc[tt][r] * 0.125f : -1e30f;      // scale = 1/sqrt(64)
    }
    float m = fmaxf(fmaxf(fmaxf(x[0], x[1]), fmaxf(x[2], x[3])), x[4]);
    m = fmaxf(m, __shfl_xor(m, 1));
    m = fmaxf(m, __shfl_xor(m, 2));
    m = fmaxf(m, __shfl_xor(m, 4));
    m = fmaxf(m, __shfl_xor(m, 8));
    float s = 0.f;
    #pragma unroll
    for (int tt = 0; tt < 5; ++tt) { x[tt] = __expf(x[tt] - m); s += x[tt]; }
    s += __shfl_xor(s, 1);
    s += __shfl_xor(s, 2);
    s += __shfl_xor(s, 4);
    s += __shfl_xor(s, 8);
    float inv = 1.0f / s;              // >= 32 valid keys -> s >= 1
    #pragma unroll
    for (int tt = 0; tt < 5; ++tt) acc[tt][r] = x[tt] * inv;
  }

  // ---- P -> LDS (bf16, A-layout target), zero-pad cols 80..95 ----
  unsigned short* Pw = &Pl[wave * 16 * P_STRIDE];
  *(uint2*)&Pw[col16 * P_STRIDE + 80 + quad * 4] = make_uint2(0u, 0u);
  #pragma unroll
  for (int tt = 0; tt < 5; ++tt)
    #pragma unroll
    for (int r = 0; r < 4; ++r)
      Pw[(quad * 4 + r) * P_STRIDE + tt * 16 + col16] = (unsigned short)f2bf(acc[tt][r]);

  // ---- PV: A=P[16 x 96], B=Vt keys [wave*16, wave*16+96) x 64 dims ----
  f32x4 oacc[4];
  #pragma unroll
  for (int nt = 0; nt < 4; ++nt) oacc[nt] = (f32x4){0.f, 0.f, 0.f, 0.f};
  #pragma unroll
  for (int ks = 0; ks < 3; ++ks) {
    short8 pa = *(const short8*)&Pw[col16 * P_STRIDE + ks * 32 + quad * 8];
    #pragma unroll
    for (int nt = 0; nt < 4; ++nt) {
      short8 vb = *(const short8*)&Vt[(nt * 16 + col16) * VT_STRIDE + wave * 16 + ks * 32 + quad * 8];
      oacc[nt] = __builtin_amdgcn_mfma_f32_16x16x32_bf16(pa, vb, oacc[nt], 0, 0, 0);
    }
  }

  // ---- Store O (fp32). C layout: row=quad*4+r (query), col=col16 (dim base) ----
  #pragma unroll
  for (int r = 0; r < 4; ++r) {
    int q = q0 + wave * 16 + quad * 4 + r;
    float* orow = og + ((size_t)(b * L_ + q) * H_ + h) * D_;
    #pragma unroll
    for (int nt = 0; nt < 4; ++nt)
      orow[nt * 16 + col16] = oacc[nt][r];
  }
}

extern "C" void kernel_launch(void* const* d_in, const int* in_sizes, int n_in,
                              void* d_out, int out_size, void* d_ws, size_t ws_size,
                              hipStream_t stream) {
  const float* q = (const float*)d_in[0];
  const float* k = (const float*)d_in[1];
  const float* v = (const float*)d_in[2];
  float* o = (float*)d_out;
  dim3 grid(L_ / 64, H_, B_);
  local_attn_mfma<<<grid, dim3(256), 0, stream>>>(q, k, v, o);
}